// Round 4
// baseline (435.989 us; speedup 1.0000x reference)
//
#include <hip/hip_runtime.h>
#include <math.h>

typedef unsigned short u16;
typedef __attribute__((ext_vector_type(8))) short bf16x8;
typedef __attribute__((ext_vector_type(4))) float f32x4;

#define MFMA16(a, b, c) __builtin_amdgcn_mfma_f32_16x16x32_bf16((a), (b), (c), 0, 0, 0)

#define B_ 2
#define S_ 2048
#define HID_ 2048
#define NH_ 16
#define NKV_ 4
#define HD_ 128
#define SCALE_ 0.08838834764831845f

static __device__ __forceinline__ u16 f2bf(float f) {
  unsigned u = __float_as_uint(f);
  u = (u + 0x7FFFu + ((u >> 16) & 1u)) >> 16;
  return (u16)u;
}

#define GLDS(src, dst)                                                        \
  __builtin_amdgcn_global_load_lds(                                           \
      (const __attribute__((address_space(1))) void*)(src),                   \
      (__attribute__((address_space(3))) void*)(dst), 16, 0, 0)

// Stage a tile (rows x (1<<CPRL) 16B-chunks per row) from global into LDS.
// LDS layout is linear with XOR swizzle baked in via pre-swizzled SOURCE
// address (global_load_lds dest must be linear: base + lane*16).
// LDS[r][bir] holds global[r][bir ^ ((r&7)<<4)].
template <int CPRL>
static __device__ __forceinline__ void stage_tile(const char* g0, long gstride,
                                                  char* lds) {
  int tid = threadIdx.x;
  int lane = tid & 63, wv = tid >> 6;
#pragma unroll
  for (int it = 0; it < 4; ++it) {
    int cb = wv * 256 + it * 64;  // wave-uniform chunk base
    int c = cb + lane;
    int r = c >> CPRL;
    int bir = (c & ((1 << CPRL) - 1)) << 4;
    int sbir = bir ^ ((r & 7) << 4);
    GLDS(g0 + (long)r * gstride + sbir, lds + cb * 16);
  }
}

// ---------------- prep kernels ----------------

__global__ __launch_bounds__(256) void conv_x(const float* __restrict__ x,
                                              u16* __restrict__ y) {
  size_t i = ((size_t)blockIdx.x * 256 + threadIdx.x) * 4;
  float4 v = *(const float4*)(x + i);
  ushort4 o = make_ushort4(f2bf(v.x), f2bf(v.y), f2bf(v.z), f2bf(v.w));
  *(ushort4*)(y + i) = o;
}

// dst[n*K + k] = bf16(src[k*N + n]);  grid: (N/32, K/32), block (32,8)
__global__ __launch_bounds__(256) void transpose_bf16(
    const float* __restrict__ src, u16* __restrict__ dst, int K, int N) {
  __shared__ float t[32][33];
  int n0 = blockIdx.x * 32, k0 = blockIdx.y * 32;
  int tx = threadIdx.x, ty = threadIdx.y;
#pragma unroll
  for (int i = 0; i < 4; ++i)
    t[ty + 8 * i][tx] = src[(size_t)(k0 + ty + 8 * i) * N + n0 + tx];
  __syncthreads();
#pragma unroll
  for (int i = 0; i < 4; ++i)
    dst[(size_t)(n0 + ty + 8 * i) * K + k0 + tx] = f2bf(t[tx][ty + 8 * i]);
}

__global__ __launch_bounds__(256) void prep_cstab(const int* __restrict__ pos,
                                                  float2* __restrict__ cs) {
  int i = blockIdx.x * 256 + threadIdx.x;  // [B*S * 64)
  int row = i >> 6, d = i & 63;
  float p = (float)pos[row];
  // inv_freq = 1e6^(-2d/128) = expf(-(2d/128)*ln(1e6))
  float inv = expf(-((float)(2 * d) * (1.0f / 128.0f)) * 13.815510557964274f);
  float a = p * inv;
  float s, c;
  sincosf(a, &s, &c);
  cs[i] = make_float2(c, s);
}

// ---------------- GEMM1: QKV projection + bias + RoPE ----------------
// C[4096,3072] = Xb[4096,2048] @ Wqkv_t^T ; BM=BN=128, BK=64
// wave tile: 32 rows x 128 cols (so RoPE pairs d,d+64 are lane-local)
// Q is additionally scaled by SCALE_ (folded out of the attention softmax).
__global__ __launch_bounds__(256) void gemm_qkv(
    const u16* __restrict__ Xb, const u16* __restrict__ Wt,
    const float* __restrict__ bq, const float* __restrict__ bk,
    const float* __restrict__ bv, const float2* __restrict__ cstab,
    u16* __restrict__ Qh, u16* __restrict__ Kh, u16* __restrict__ Vt) {
  __shared__ __align__(16) char As[16384];
  __shared__ __align__(16) char Bs[16384];
  int bm = blockIdx.x, bn = blockIdx.y;
  int tid = threadIdx.x, lane = tid & 63, w = tid >> 6;
  int l16 = lane & 15, ln4 = lane >> 4;

  f32x4 acc[2][8] = {};

  for (int kt = 0; kt < 32; ++kt) {
    __syncthreads();
    stage_tile<3>((const char*)(Xb + (size_t)bm * 128 * 2048 + kt * 64), 4096,
                  As);
    stage_tile<3>((const char*)(Wt + (size_t)bn * 128 * 2048 + kt * 64), 4096,
                  Bs);
    __syncthreads();
#pragma unroll
    for (int kk = 0; kk < 2; ++kk) {
      bf16x8 a[2], b[8];
#pragma unroll
      for (int m = 0; m < 2; ++m) {
        int r = w * 32 + m * 16 + l16;
        int off = r * 128 + ((kk * 64 + ln4 * 16) ^ ((r & 7) << 4));
        a[m] = *(const bf16x8*)(As + off);
      }
#pragma unroll
      for (int n = 0; n < 8; ++n) {
        int r = n * 16 + l16;
        int off = r * 128 + ((kk * 64 + ln4 * 16) ^ ((r & 7) << 4));
        b[n] = *(const bf16x8*)(Bs + off);
      }
#pragma unroll
      for (int m = 0; m < 2; ++m)
#pragma unroll
        for (int n = 0; n < 8; ++n) acc[m][n] = MFMA16(a[m], b[n], acc[m][n]);
    }
  }

  // epilogue: bias + RoPE + scatter to Q/K/V buffers
  int region, hh;
  const float* bias;
  if (bn < 16) {
    region = 0; hh = bn; bias = bq;
  } else if (bn < 20) {
    region = 1; hh = bn - 16; bias = bk;
  } else {
    region = 2; hh = bn - 20; bias = bv;
  }
  float postscale = (region == 0) ? SCALE_ : 1.0f;

#pragma unroll
  for (int bi = 0; bi < 4; ++bi) {
    int dlo = bi * 16 + l16;  // 0..63
    float blo = bias[hh * 128 + dlo];
    float bhi = bias[hh * 128 + dlo + 64];
#pragma unroll
    for (int m = 0; m < 2; ++m) {
      int rbase = bm * 128 + w * 32 + m * 16 + ln4 * 4;
      int bb = rbase >> 11;   // batch
      int s0 = rbase & 2047;  // seq
      if (region == 2) {
        // V: no rope; transposed store Vt[b][kvh][d][s], 4 consecutive s
        u16 pl[4], ph[4];
#pragma unroll
        for (int reg = 0; reg < 4; ++reg) {
          pl[reg] = f2bf(acc[m][bi][reg] + blo);
          ph[reg] = f2bf(acc[m][bi + 4][reg] + bhi);
        }
        size_t base = ((size_t)(bb * NKV_ + hh) * 128 + dlo) * 2048 + s0;
        *(ushort4*)(Vt + base) = make_ushort4(pl[0], pl[1], pl[2], pl[3]);
        *(ushort4*)(Vt + base + (size_t)64 * 2048) =
            make_ushort4(ph[0], ph[1], ph[2], ph[3]);
      } else {
#pragma unroll
        for (int reg = 0; reg < 4; ++reg) {
          int rg = rbase + reg;
          int s = rg & 2047;
          float vlo = acc[m][bi][reg] + blo;
          float vhi = acc[m][bi + 4][reg] + bhi;
          float2 cs = cstab[(size_t)rg * 64 + dlo];
          float nl = (vlo * cs.x - vhi * cs.y) * postscale;
          float nh = (vhi * cs.x + vlo * cs.y) * postscale;
          u16* dst = (region == 0)
                         ? Qh + ((size_t)(bb * NH_ + hh) * 2048 + s) * 128
                         : Kh + ((size_t)(bb * NKV_ + hh) * 2048 + s) * 128;
          dst[dlo] = f2bf(nl);
          dst[dlo + 64] = f2bf(nh);
        }
      }
    }
  }
}

// ---------------- attention: causal GQA flash, barrier-free ----------------
// One wave (64 threads) per block; wave owns 32 q-rows (2 M-frags).
// K/V fragments read DIRECTLY from global (L2-resident per XCD thanks to
// bid&7 -> (b,kvh) swizzle; each XCD's KV working set is ~1MB). No
// __syncthreads anywhere; only a 4KB wave-private LDS buffer for P.
// Defer-max: shuffle-free skip test (local max vs mrow+8); full reduce +
// O-rescale only when some row's max grew (first tile, rarely after).
__global__ __launch_bounds__(64, 3) void attn(const u16* __restrict__ Qh,
                                              const u16* __restrict__ Kh,
                                              const u16* __restrict__ Vt,
                                              u16* __restrict__ ctx) {
  __shared__ __align__(16) char Ps[4096];  // [32 q][64 kv] u16, XOR-swizzled
  int bid = blockIdx.x;
  int x = bid & 7;  // XCD group = (b, kvh)
  int b = x >> 2, kvh = x & 3;
  int i = bid >> 3;          // 0..255 within XCD group
  int hl = i & 3;            // head within kv group
  int qt = 63 - (i >> 2);    // LPT: heavy q-tiles dispatch first
  int h = kvh * 4 + hl;
  int qw0 = qt * 32;
  int nt = (qw0 >> 6) + 1;   // causal kv-tile count (KVBLK=64)

  int lane = threadIdx.x & 63;
  int l16 = lane & 15, ln4 = lane >> 4;

  const u16* Kb = Kh + (size_t)(b * NKV_ + kvh) * S_ * HD_;
  const u16* Vb = Vt + (size_t)(b * NKV_ + kvh) * HD_ * S_;
  const u16* Qb = Qh + (size_t)(b * NH_ + h) * S_ * HD_;

  // Q fragments (Q pre-scaled by SCALE_): rows qw0 + m*16 + l16
  bf16x8 qf[2][4];
#pragma unroll
  for (int m = 0; m < 2; ++m)
#pragma unroll
    for (int kk = 0; kk < 4; ++kk)
      qf[m][kk] = *(const bf16x8*)(Qb + (size_t)(qw0 + m * 16 + l16) * 128 +
                                   kk * 32 + ln4 * 8);

  f32x4 oacc[2][8] = {};
  float mrow[8], lsum[8];  // [m*4+reg]; lsum = per-lane partial (own kv cols)
#pragma unroll
  for (int r = 0; r < 8; ++r) {
    mrow[r] = -1e30f;
    lsum[r] = 0.0f;
  }

#pragma unroll 1
  for (int t = 0; t < nt; ++t) {
    int kvb = t * 64;

    // ---- S = Q K^T (K-frags straight from L2) ----
    f32x4 sa[2][4] = {};
#pragma unroll
    for (int kk = 0; kk < 4; ++kk) {
      bf16x8 kf[4];
#pragma unroll
      for (int n = 0; n < 4; ++n)
        kf[n] = *(const bf16x8*)(Kb + (size_t)(kvb + n * 16 + l16) * 128 +
                                 kk * 32 + ln4 * 8);
      __builtin_amdgcn_s_setprio(1);
#pragma unroll
      for (int m = 0; m < 2; ++m)
#pragma unroll
        for (int n = 0; n < 4; ++n)
          sa[m][n] = MFMA16(qf[m][kk], kf[n], sa[m][n]);
      __builtin_amdgcn_s_setprio(0);
    }

    // causal mask (only ever needed on the last tile)
    if (t == nt - 1) {
#pragma unroll
      for (int m = 0; m < 2; ++m)
#pragma unroll
        for (int n = 0; n < 4; ++n)
#pragma unroll
          for (int reg = 0; reg < 4; ++reg)
            if (kvb + n * 16 + l16 > qw0 + m * 16 + ln4 * 4 + reg)
              sa[m][n][reg] = -1e30f;
    }

    // ---- shuffle-free defer-max test ----
    float tloc[8];
    int ok = 1;
#pragma unroll
    for (int m = 0; m < 2; ++m)
#pragma unroll
      for (int reg = 0; reg < 4; ++reg) {
        int r = m * 4 + reg;
        tloc[r] = fmaxf(fmaxf(sa[m][0][reg], sa[m][1][reg]),
                        fmaxf(sa[m][2][reg], sa[m][3][reg]));
        ok &= (tloc[r] <= mrow[r] + 8.0f);
      }
    if (!__all(ok)) {
      // slow path: full row-max reduce, rescale O and lsum
#pragma unroll
      for (int r = 0; r < 8; ++r) {
        float tm = tloc[r];
#pragma unroll
        for (int mk = 1; mk < 16; mk <<= 1) tm = fmaxf(tm, __shfl_xor(tm, mk));
        float mnew = fmaxf(mrow[r], tm);
        float scl = __expf(mrow[r] - mnew);
        mrow[r] = mnew;
        lsum[r] *= scl;
        int m = r >> 2, reg = r & 3;
#pragma unroll
        for (int nf = 0; nf < 8; ++nf) oacc[m][nf][reg] *= scl;
      }
    }

    // ---- P = exp(S - m), store to wave-private LDS, per-lane lsum ----
#pragma unroll
    for (int m = 0; m < 2; ++m)
#pragma unroll
      for (int reg = 0; reg < 4; ++reg) {
        int r = m * 4 + reg;
        int prow = m * 16 + ln4 * 4 + reg;
        float rs = 0.0f;
#pragma unroll
        for (int n = 0; n < 4; ++n) {
          float p = __expf(sa[m][n][reg] - mrow[r]);
          rs += p;
          int off = prow * 128 + ((2 * (n * 16 + l16)) ^ ((prow & 7) << 4));
          *(u16*)(Ps + off) = f2bf(p);
        }
        lsum[r] += rs;
      }

    // ---- O += P V (V-frags straight from L2) ----
#pragma unroll
    for (int kc = 0; kc < 2; ++kc) {
      bf16x8 pa[2];
#pragma unroll
      for (int m = 0; m < 2; ++m) {
        int ar = m * 16 + l16;
        pa[m] = *(const bf16x8*)(Ps + ar * 128 +
                                 ((kc * 64 + ln4 * 16) ^ ((ar & 7) << 4)));
      }
      bf16x8 vf[8];
#pragma unroll
      for (int nf = 0; nf < 8; ++nf)
        vf[nf] = *(const bf16x8*)(Vb + (size_t)(nf * 16 + l16) * 2048 + kvb +
                                  kc * 32 + ln4 * 8);
      __builtin_amdgcn_s_setprio(1);
#pragma unroll
      for (int nf = 0; nf < 8; ++nf)
#pragma unroll
        for (int m = 0; m < 2; ++m)
          oacc[m][nf] = MFMA16(pa[m], vf[nf], oacc[m][nf]);
      __builtin_amdgcn_s_setprio(0);
    }
  }

  // ---- epilogue: reduce per-lane lsum partials across the row's 16 lanes ----
#pragma unroll
  for (int r = 0; r < 8; ++r) {
#pragma unroll
    for (int mk = 1; mk < 16; mk <<= 1) lsum[r] += __shfl_xor(lsum[r], mk);
  }
#pragma unroll
  for (int m = 0; m < 2; ++m)
#pragma unroll
    for (int reg = 0; reg < 4; ++reg) {
      float inv = 1.0f / lsum[m * 4 + reg];
      int s = qw0 + m * 16 + ln4 * 4 + reg;
#pragma unroll
      for (int nf = 0; nf < 8; ++nf) {
        ctx[((size_t)(b * 2048 + s)) * 2048 + h * 128 + nf * 16 + l16] =
            f2bf(oacc[m][nf][reg] * inv);
      }
    }
}

// ---------------- GEMM2: out = ctx @ Wo (fp32 out) ----------------
__global__ __launch_bounds__(256) void gemm_out(const u16* __restrict__ Ab,
                                                const u16* __restrict__ Wt,
                                                float* __restrict__ out) {
  __shared__ __align__(16) char As[16384];
  __shared__ __align__(16) char Bs[16384];
  int bm = blockIdx.x, bn = blockIdx.y;
  int tid = threadIdx.x, lane = tid & 63, w = tid >> 6;
  int l16 = lane & 15, ln4 = lane >> 4;
  int wr = (w >> 1) * 64, wc = (w & 1) * 64;

  f32x4 acc[4][4] = {};

  for (int kt = 0; kt < 32; ++kt) {
    __syncthreads();
    stage_tile<3>((const char*)(Ab + (size_t)bm * 128 * 2048 + kt * 64), 4096,
                  As);
    stage_tile<3>((const char*)(Wt + (size_t)bn * 128 * 2048 + kt * 64), 4096,
                  Bs);
    __syncthreads();
#pragma unroll
    for (int kk = 0; kk < 2; ++kk) {
      bf16x8 a[4], b[4];
#pragma unroll
      for (int m = 0; m < 4; ++m) {
        int r = wr + m * 16 + l16;
        int off = r * 128 + ((kk * 64 + ln4 * 16) ^ ((r & 7) << 4));
        a[m] = *(const bf16x8*)(As + off);
      }
#pragma unroll
      for (int n = 0; n < 4; ++n) {
        int r = wc + n * 16 + l16;
        int off = r * 128 + ((kk * 64 + ln4 * 16) ^ ((r & 7) << 4));
        b[n] = *(const bf16x8*)(Bs + off);
      }
#pragma unroll
      for (int m = 0; m < 4; ++m)
#pragma unroll
        for (int n = 0; n < 4; ++n) acc[m][n] = MFMA16(a[m], b[n], acc[m][n]);
    }
  }

#pragma unroll
  for (int m = 0; m < 4; ++m)
#pragma unroll
    for (int n = 0; n < 4; ++n)
#pragma unroll
      for (int reg = 0; reg < 4; ++reg) {
        int row = bm * 128 + wr + m * 16 + ln4 * 4 + reg;
        int col = bn * 128 + wc + n * 16 + l16;
        out[(size_t)row * 2048 + col] = acc[m][n][reg];
      }
}

// ---------------- launch ----------------

extern "C" void kernel_launch(void* const* d_in, const int* in_sizes, int n_in,
                              void* d_out, int out_size, void* d_ws,
                              size_t ws_size, hipStream_t stream) {
  const float* hid = (const float*)d_in[0];
  const int* pos = (const int*)d_in[1];
  const float* Wq = (const float*)d_in[2];
  const float* bq = (const float*)d_in[3];
  const float* Wk = (const float*)d_in[4];
  const float* bk = (const float*)d_in[5];
  const float* Wv = (const float*)d_in[6];
  const float* bv = (const float*)d_in[7];
  const float* Wo = (const float*)d_in[8];
  float* out = (float*)d_out;

  char* ws = (char*)d_ws;
  u16* Xb = (u16*)(ws + 0);                    // 16.78 MB  [4096][2048] bf16
  u16* Wqkvt = (u16*)(ws + 16777216UL);        // 12.58 MB  [3072][2048] bf16
  u16* Wot = (u16*)(ws + 29360128UL);          //  8.39 MB  [2048][2048] bf16
  u16* Qh = (u16*)(ws + 37748736UL);           // 16.78 MB  [B][NH][S][D]
  u16* Kh = (u16*)(ws + 54525952UL);           //  4.19 MB  [B][NKV][S][D]
  u16* Vt = (u16*)(ws + 58720256UL);           //  4.19 MB  [B][NKV][D][S]
  float2* cstab = (float2*)(ws + 62914560UL);  //  2.10 MB  [B*S][64]
  u16* ctx = Xb;  // alias: Xb dead after gemm_qkv

  conv_x<<<8192, 256, 0, stream>>>(hid, Xb);
  transpose_bf16<<<dim3(64, 64), dim3(32, 8), 0, stream>>>(Wq, Wqkvt, 2048,
                                                           2048);
  transpose_bf16<<<dim3(16, 64), dim3(32, 8), 0, stream>>>(
      Wk, Wqkvt + (size_t)2048 * 2048, 2048, 512);
  transpose_bf16<<<dim3(16, 64), dim3(32, 8), 0, stream>>>(
      Wv, Wqkvt + (size_t)2560 * 2048, 2048, 512);
  transpose_bf16<<<dim3(64, 64), dim3(32, 8), 0, stream>>>(Wo, Wot, 2048, 2048);
  prep_cstab<<<1024, 256, 0, stream>>>(pos, cstab);

  gemm_qkv<<<dim3(32, 24), 256, 0, stream>>>(Xb, Wqkvt, bq, bk, bv, cstab, Qh,
                                             Kh, Vt);
  attn<<<2048, 64, 0, stream>>>(Qh, Kh, Vt, ctx);
  gemm_out<<<dim3(32, 16), 256, 0, stream>>>(ctx, Wot, out);
}

// Round 5
// 220.371 us; speedup vs baseline: 1.9784x; 1.9784x over previous
//
#include <hip/hip_runtime.h>
#include <math.h>

typedef unsigned short u16;
typedef __attribute__((ext_vector_type(8))) short bf16x8;
typedef __attribute__((ext_vector_type(4))) float f32x4;

#define MFMA16(a, b, c) __builtin_amdgcn_mfma_f32_16x16x32_bf16((a), (b), (c), 0, 0, 0)

#define B_ 2
#define S_ 2048
#define HID_ 2048
#define NH_ 16
#define NKV_ 4
#define HD_ 128
#define SCALE_ 0.08838834764831845f

static __device__ __forceinline__ u16 f2bf(float f) {
  unsigned u = __float_as_uint(f);
  u = (u + 0x7FFFu + ((u >> 16) & 1u)) >> 16;
  return (u16)u;
}

#define GLDS(src, dst)                                                        \
  __builtin_amdgcn_global_load_lds(                                           \
      (const __attribute__((address_space(1))) void*)(src),                   \
      (__attribute__((address_space(3))) void*)(dst), 16, 0, 0)

// Stage a tile (rows x (1<<CPRL) 16B-chunks per row) from global into LDS.
// LDS layout is linear with XOR swizzle baked in via pre-swizzled SOURCE
// address (global_load_lds dest must be linear: base + lane*16).
// LDS[r][bir] holds global[r][bir ^ ((r&7)<<4)].
template <int CPRL>
static __device__ __forceinline__ void stage_tile(const char* g0, long gstride,
                                                  char* lds) {
  int tid = threadIdx.x;
  int lane = tid & 63, wv = tid >> 6;
#pragma unroll
  for (int it = 0; it < 4; ++it) {
    int cb = wv * 256 + it * 64;  // wave-uniform chunk base
    int c = cb + lane;
    int r = c >> CPRL;
    int bir = (c & ((1 << CPRL) - 1)) << 4;
    int sbir = bir ^ ((r & 7) << 4);
    GLDS(g0 + (long)r * gstride + sbir, lds + cb * 16);
  }
}

// ---------------- prep kernels ----------------

__global__ __launch_bounds__(256) void conv_x(const float* __restrict__ x,
                                              u16* __restrict__ y) {
  size_t i = ((size_t)blockIdx.x * 256 + threadIdx.x) * 4;
  float4 v = *(const float4*)(x + i);
  ushort4 o = make_ushort4(f2bf(v.x), f2bf(v.y), f2bf(v.z), f2bf(v.w));
  *(ushort4*)(y + i) = o;
}

// dst[n*K + k] = bf16(src[k*N + n]);  grid: (N/32, K/32), block (32,8)
__global__ __launch_bounds__(256) void transpose_bf16(
    const float* __restrict__ src, u16* __restrict__ dst, int K, int N) {
  __shared__ float t[32][33];
  int n0 = blockIdx.x * 32, k0 = blockIdx.y * 32;
  int tx = threadIdx.x, ty = threadIdx.y;
#pragma unroll
  for (int i = 0; i < 4; ++i)
    t[ty + 8 * i][tx] = src[(size_t)(k0 + ty + 8 * i) * N + n0 + tx];
  __syncthreads();
#pragma unroll
  for (int i = 0; i < 4; ++i)
    dst[(size_t)(n0 + ty + 8 * i) * K + k0 + tx] = f2bf(t[tx][ty + 8 * i]);
}

__global__ __launch_bounds__(256) void prep_cstab(const int* __restrict__ pos,
                                                  float2* __restrict__ cs) {
  int i = blockIdx.x * 256 + threadIdx.x;  // [B*S * 64)
  int row = i >> 6, d = i & 63;
  float p = (float)pos[row];
  // inv_freq = 1e6^(-2d/128) = expf(-(2d/128)*ln(1e6))
  float inv = expf(-((float)(2 * d) * (1.0f / 128.0f)) * 13.815510557964274f);
  float a = p * inv;
  float s, c;
  sincosf(a, &s, &c);
  cs[i] = make_float2(c, s);
}

// ---------------- GEMM1: QKV projection + bias + RoPE ----------------
// C[4096,3072] = Xb[4096,2048] @ Wqkv_t^T ; BM=BN=128, BK=64
// wave tile: 32 rows x 128 cols (so RoPE pairs d,d+64 are lane-local)
// Q is additionally scaled by SCALE_ (folded out of the attention softmax).
__global__ __launch_bounds__(256) void gemm_qkv(
    const u16* __restrict__ Xb, const u16* __restrict__ Wt,
    const float* __restrict__ bq, const float* __restrict__ bk,
    const float* __restrict__ bv, const float2* __restrict__ cstab,
    u16* __restrict__ Qh, u16* __restrict__ Kh, u16* __restrict__ Vt) {
  __shared__ __align__(16) char As[16384];
  __shared__ __align__(16) char Bs[16384];
  int bm = blockIdx.x, bn = blockIdx.y;
  int tid = threadIdx.x, lane = tid & 63, w = tid >> 6;
  int l16 = lane & 15, ln4 = lane >> 4;

  f32x4 acc[2][8] = {};

  for (int kt = 0; kt < 32; ++kt) {
    __syncthreads();
    stage_tile<3>((const char*)(Xb + (size_t)bm * 128 * 2048 + kt * 64), 4096,
                  As);
    stage_tile<3>((const char*)(Wt + (size_t)bn * 128 * 2048 + kt * 64), 4096,
                  Bs);
    __syncthreads();
#pragma unroll
    for (int kk = 0; kk < 2; ++kk) {
      bf16x8 a[2], b[8];
#pragma unroll
      for (int m = 0; m < 2; ++m) {
        int r = w * 32 + m * 16 + l16;
        int off = r * 128 + ((kk * 64 + ln4 * 16) ^ ((r & 7) << 4));
        a[m] = *(const bf16x8*)(As + off);
      }
#pragma unroll
      for (int n = 0; n < 8; ++n) {
        int r = n * 16 + l16;
        int off = r * 128 + ((kk * 64 + ln4 * 16) ^ ((r & 7) << 4));
        b[n] = *(const bf16x8*)(Bs + off);
      }
#pragma unroll
      for (int m = 0; m < 2; ++m)
#pragma unroll
        for (int n = 0; n < 8; ++n) acc[m][n] = MFMA16(a[m], b[n], acc[m][n]);
    }
  }

  // epilogue: bias + RoPE + scatter to Q/K/V buffers
  int region, hh;
  const float* bias;
  if (bn < 16) {
    region = 0; hh = bn; bias = bq;
  } else if (bn < 20) {
    region = 1; hh = bn - 16; bias = bk;
  } else {
    region = 2; hh = bn - 20; bias = bv;
  }
  float postscale = (region == 0) ? SCALE_ : 1.0f;

#pragma unroll
  for (int bi = 0; bi < 4; ++bi) {
    int dlo = bi * 16 + l16;  // 0..63
    float blo = bias[hh * 128 + dlo];
    float bhi = bias[hh * 128 + dlo + 64];
#pragma unroll
    for (int m = 0; m < 2; ++m) {
      int rbase = bm * 128 + w * 32 + m * 16 + ln4 * 4;
      int bb = rbase >> 11;   // batch
      int s0 = rbase & 2047;  // seq
      if (region == 2) {
        // V: no rope; transposed store Vt[b][kvh][d][s], 4 consecutive s
        u16 pl[4], ph[4];
#pragma unroll
        for (int reg = 0; reg < 4; ++reg) {
          pl[reg] = f2bf(acc[m][bi][reg] + blo);
          ph[reg] = f2bf(acc[m][bi + 4][reg] + bhi);
        }
        size_t base = ((size_t)(bb * NKV_ + hh) * 128 + dlo) * 2048 + s0;
        *(ushort4*)(Vt + base) = make_ushort4(pl[0], pl[1], pl[2], pl[3]);
        *(ushort4*)(Vt + base + (size_t)64 * 2048) =
            make_ushort4(ph[0], ph[1], ph[2], ph[3]);
      } else {
#pragma unroll
        for (int reg = 0; reg < 4; ++reg) {
          int rg = rbase + reg;
          int s = rg & 2047;
          float vlo = acc[m][bi][reg] + blo;
          float vhi = acc[m][bi + 4][reg] + bhi;
          float2 cs = cstab[(size_t)rg * 64 + dlo];
          float nl = (vlo * cs.x - vhi * cs.y) * postscale;
          float nh = (vhi * cs.x + vlo * cs.y) * postscale;
          u16* dst = (region == 0)
                         ? Qh + ((size_t)(bb * NH_ + hh) * 2048 + s) * 128
                         : Kh + ((size_t)(bb * NKV_ + hh) * 2048 + s) * 128;
          dst[dlo] = f2bf(nl);
          dst[dlo + 64] = f2bf(nh);
        }
      }
    }
  }
}

// ---------------- attention: causal GQA flash ----------------
// R1 structure (4 waves, single-buffered 40KB LDS, 4 blocks/CU) with:
//  * XCD pinning: bid&7 -> (b,kvh). Blocks round-robin to XCDs by bid, so
//    each XCD's L2 sees ONE (b,kvh) K/V set (2MB, fits 4MB L2) instead of
//    all 8 (16MB, L3-thrash). Staging re-reads served from L2, not L3.
//  * Defer-max softmax (T13): shuffle-free skip test vs mrow+8; slow path
//    (full 16-lane max reduce + O/lsum rescale) only when a row max grows
//    (always tile 0, rarely after). lsum kept as per-lane partials,
//    reduced once in the epilogue.
__global__ __launch_bounds__(256) void attn(const u16* __restrict__ Qh,
                                            const u16* __restrict__ Kh,
                                            const u16* __restrict__ Vt,
                                            u16* __restrict__ ctx) {
  __shared__ __align__(16) char Ks[16384];   // [64 kv][128 d] swizzled
  __shared__ __align__(16) char Vs[16384];   // [128 d][64 kv] swizzled
  __shared__ __align__(16) char Ps[4][2048]; // per-wave [16 q][64 kv]
  int bid = blockIdx.x;
  int x = bid & 7;           // XCD group = (b, kvh)
  int b = x >> 2, kvh = x & 3;
  int i = bid >> 3;          // 0..127 within XCD group
  int hl = i & 3;            // head within kv group
  int qt = 31 - (i >> 2);    // heavy q-tiles first (harmless)
  int h = kvh * 4 + hl;
  int q0 = qt * 64;
  int nt = qt + 1;

  int tid = threadIdx.x, lane = tid & 63, w = tid >> 6;
  int l16 = lane & 15, ln4 = lane >> 4;

  // Q fragments (registers), rows q0+w*16+l16  (Q pre-scaled by SCALE_)
  bf16x8 qf[4];
  const u16* qrow = Qh + ((size_t)(b * NH_ + h) * 2048 + q0 + w * 16 + l16) * 128;
#pragma unroll
  for (int kk = 0; kk < 4; ++kk)
    qf[kk] = *(const bf16x8*)(qrow + kk * 32 + ln4 * 8);

  f32x4 oacc[8] = {};
  float mrow[4], lsum[4];  // row = ln4*4+reg; lsum = per-lane partial
#pragma unroll
  for (int r = 0; r < 4; ++r) {
    mrow[r] = -1e30f;
    lsum[r] = 0.0f;
  }

  const char* kbase = (const char*)(Kh + (size_t)(b * NKV_ + kvh) * 2048 * 128);
  const char* vbase = (const char*)(Vt + (size_t)(b * NKV_ + kvh) * 128 * 2048);

#pragma unroll 1
  for (int t = 0; t < nt; ++t) {
    __syncthreads();
    stage_tile<4>(kbase + (size_t)t * 64 * 256, 256, Ks);
    stage_tile<3>(vbase + (size_t)t * 128, 4096, Vs);
    __syncthreads();

    // S = Q K^T
    f32x4 sa[4] = {};
    __builtin_amdgcn_s_setprio(1);
#pragma unroll
    for (int kk = 0; kk < 4; ++kk) {
      bf16x8 kf[4];
#pragma unroll
      for (int n = 0; n < 4; ++n) {
        int r = n * 16 + l16;
        int off = r * 256 + ((kk * 64 + ln4 * 16) ^ ((r & 7) << 4));
        kf[n] = *(const bf16x8*)(Ks + off);
      }
#pragma unroll
      for (int n = 0; n < 4; ++n) sa[n] = MFMA16(qf[kk], kf[n], sa[n]);
    }
    __builtin_amdgcn_s_setprio(0);

    // causal mask (only the diagonal tile needs it)
    if (t == nt - 1) {
#pragma unroll
      for (int n = 0; n < 4; ++n)
#pragma unroll
        for (int reg = 0; reg < 4; ++reg)
          if (t * 64 + n * 16 + l16 > q0 + w * 16 + ln4 * 4 + reg)
            sa[n][reg] = -1e30f;
    }

    // shuffle-free defer-max test
    float tloc[4];
    int ok = 1;
#pragma unroll
    for (int reg = 0; reg < 4; ++reg) {
      tloc[reg] = fmaxf(fmaxf(sa[0][reg], sa[1][reg]),
                        fmaxf(sa[2][reg], sa[3][reg]));
      ok &= (tloc[reg] <= mrow[reg] + 8.0f);
    }
    if (!__all(ok)) {
      // slow path: full row-max reduce + rescale O and lsum
#pragma unroll
      for (int reg = 0; reg < 4; ++reg) {
        float tm = tloc[reg];
#pragma unroll
        for (int mk = 1; mk < 16; mk <<= 1) tm = fmaxf(tm, __shfl_xor(tm, mk));
        float mnew = fmaxf(mrow[reg], tm);
        float scl = __expf(mrow[reg] - mnew);
        mrow[reg] = mnew;
        lsum[reg] *= scl;
#pragma unroll
        for (int nf = 0; nf < 8; ++nf) oacc[nf][reg] *= scl;
      }
    }

    // P = exp(S - m) -> wave-private LDS; per-lane lsum partials
#pragma unroll
    for (int reg = 0; reg < 4; ++reg) {
      int prow = ln4 * 4 + reg;
      float rs = 0.0f;
#pragma unroll
      for (int n = 0; n < 4; ++n) {
        float p = __expf(sa[n][reg] - mrow[reg]);
        rs += p;
        int off = prow * 128 + ((2 * (n * 16 + l16)) ^ ((prow & 7) << 4));
        *(u16*)(Ps[w] + off) = f2bf(p);
      }
      lsum[reg] += rs;
    }

    // O += P V   (A = P from wave-private LDS, B = Vt)
    __builtin_amdgcn_s_setprio(1);
#pragma unroll
    for (int kc = 0; kc < 2; ++kc) {
      int offa = l16 * 128 + ((kc * 64 + ln4 * 16) ^ ((l16 & 7) << 4));
      bf16x8 pa = *(const bf16x8*)(Ps[w] + offa);
#pragma unroll
      for (int nf = 0; nf < 8; ++nf) {
        int r = nf * 16 + l16;
        int off = r * 128 + ((kc * 64 + ln4 * 16) ^ ((r & 7) << 4));
        bf16x8 vf = *(const bf16x8*)(Vs + off);
        oacc[nf] = MFMA16(pa, vf, oacc[nf]);
      }
    }
    __builtin_amdgcn_s_setprio(0);
  }

  // epilogue: reduce per-lane lsum partials across the row's 16 lanes
#pragma unroll
  for (int reg = 0; reg < 4; ++reg) {
#pragma unroll
    for (int mk = 1; mk < 16; mk <<= 1)
      lsum[reg] += __shfl_xor(lsum[reg], mk);
  }
#pragma unroll
  for (int reg = 0; reg < 4; ++reg) {
    float inv = 1.0f / lsum[reg];
    int s = q0 + w * 16 + ln4 * 4 + reg;
#pragma unroll
    for (int nf = 0; nf < 8; ++nf) {
      ctx[((size_t)(b * 2048 + s)) * 2048 + h * 128 + nf * 16 + l16] =
          f2bf(oacc[nf][reg] * inv);
    }
  }
}

// ---------------- GEMM2: out = ctx @ Wo (fp32 out) ----------------
__global__ __launch_bounds__(256) void gemm_out(const u16* __restrict__ Ab,
                                                const u16* __restrict__ Wt,
                                                float* __restrict__ out) {
  __shared__ __align__(16) char As[16384];
  __shared__ __align__(16) char Bs[16384];
  int bm = blockIdx.x, bn = blockIdx.y;
  int tid = threadIdx.x, lane = tid & 63, w = tid >> 6;
  int l16 = lane & 15, ln4 = lane >> 4;
  int wr = (w >> 1) * 64, wc = (w & 1) * 64;

  f32x4 acc[4][4] = {};

  for (int kt = 0; kt < 32; ++kt) {
    __syncthreads();
    stage_tile<3>((const char*)(Ab + (size_t)bm * 128 * 2048 + kt * 64), 4096,
                  As);
    stage_tile<3>((const char*)(Wt + (size_t)bn * 128 * 2048 + kt * 64), 4096,
                  Bs);
    __syncthreads();
#pragma unroll
    for (int kk = 0; kk < 2; ++kk) {
      bf16x8 a[4], b[4];
#pragma unroll
      for (int m = 0; m < 4; ++m) {
        int r = wr + m * 16 + l16;
        int off = r * 128 + ((kk * 64 + ln4 * 16) ^ ((r & 7) << 4));
        a[m] = *(const bf16x8*)(As + off);
      }
#pragma unroll
      for (int n = 0; n < 4; ++n) {
        int r = wc + n * 16 + l16;
        int off = r * 128 + ((kk * 64 + ln4 * 16) ^ ((r & 7) << 4));
        b[n] = *(const bf16x8*)(Bs + off);
      }
#pragma unroll
      for (int m = 0; m < 4; ++m)
#pragma unroll
        for (int n = 0; n < 4; ++n) acc[m][n] = MFMA16(a[m], b[n], acc[m][n]);
    }
  }

#pragma unroll
  for (int m = 0; m < 4; ++m)
#pragma unroll
    for (int n = 0; n < 4; ++n)
#pragma unroll
      for (int reg = 0; reg < 4; ++reg) {
        int row = bm * 128 + wr + m * 16 + ln4 * 4 + reg;
        int col = bn * 128 + wc + n * 16 + l16;
        out[(size_t)row * 2048 + col] = acc[m][n][reg];
      }
}

// ---------------- launch ----------------

extern "C" void kernel_launch(void* const* d_in, const int* in_sizes, int n_in,
                              void* d_out, int out_size, void* d_ws,
                              size_t ws_size, hipStream_t stream) {
  const float* hid = (const float*)d_in[0];
  const int* pos = (const int*)d_in[1];
  const float* Wq = (const float*)d_in[2];
  const float* bq = (const float*)d_in[3];
  const float* Wk = (const float*)d_in[4];
  const float* bk = (const float*)d_in[5];
  const float* Wv = (const float*)d_in[6];
  const float* bv = (const float*)d_in[7];
  const float* Wo = (const float*)d_in[8];
  float* out = (float*)d_out;

  char* ws = (char*)d_ws;
  u16* Xb = (u16*)(ws + 0);                    // 16.78 MB  [4096][2048] bf16
  u16* Wqkvt = (u16*)(ws + 16777216UL);        // 12.58 MB  [3072][2048] bf16
  u16* Wot = (u16*)(ws + 29360128UL);          //  8.39 MB  [2048][2048] bf16
  u16* Qh = (u16*)(ws + 37748736UL);           // 16.78 MB  [B][NH][S][D]
  u16* Kh = (u16*)(ws + 54525952UL);           //  4.19 MB  [B][NKV][S][D]
  u16* Vt = (u16*)(ws + 58720256UL);           //  4.19 MB  [B][NKV][D][S]
  float2* cstab = (float2*)(ws + 62914560UL);  //  2.10 MB  [B*S][64]
  u16* ctx = Xb;  // alias: Xb dead after gemm_qkv

  conv_x<<<8192, 256, 0, stream>>>(hid, Xb);
  transpose_bf16<<<dim3(64, 64), dim3(32, 8), 0, stream>>>(Wq, Wqkvt, 2048,
                                                           2048);
  transpose_bf16<<<dim3(16, 64), dim3(32, 8), 0, stream>>>(
      Wk, Wqkvt + (size_t)2048 * 2048, 2048, 512);
  transpose_bf16<<<dim3(16, 64), dim3(32, 8), 0, stream>>>(
      Wv, Wqkvt + (size_t)2560 * 2048, 2048, 512);
  transpose_bf16<<<dim3(64, 64), dim3(32, 8), 0, stream>>>(Wo, Wot, 2048, 2048);
  prep_cstab<<<1024, 256, 0, stream>>>(pos, cstab);

  gemm_qkv<<<dim3(32, 24), 256, 0, stream>>>(Xb, Wqkvt, bq, bk, bv, cstab, Qh,
                                             Kh, Vt);
  attn<<<1024, 256, 0, stream>>>(Qh, Kh, Vt, ctx);
  gemm_out<<<dim3(32, 16), 256, 0, stream>>>(ctx, Wot, out);
}

// Round 6
// 210.857 us; speedup vs baseline: 2.0677x; 1.0451x over previous
//
#include <hip/hip_runtime.h>
#include <math.h>

typedef unsigned short u16;
typedef __attribute__((ext_vector_type(8))) short bf16x8;
typedef __attribute__((ext_vector_type(4))) float f32x4;

#define MFMA16(a, b, c) __builtin_amdgcn_mfma_f32_16x16x32_bf16((a), (b), (c), 0, 0, 0)

#define B_ 2
#define S_ 2048
#define HID_ 2048
#define NH_ 16
#define NKV_ 4
#define HD_ 128
#define SCALE_ 0.08838834764831845f

static __device__ __forceinline__ u16 f2bf(float f) {
  unsigned u = __float_as_uint(f);
  u = (u + 0x7FFFu + ((u >> 16) & 1u)) >> 16;
  return (u16)u;
}

#define GLDS(src, dst)                                                        \
  __builtin_amdgcn_global_load_lds(                                           \
      (const __attribute__((address_space(1))) void*)(src),                   \
      (__attribute__((address_space(3))) void*)(dst), 16, 0, 0)

#define WAITV(N) asm volatile("s_waitcnt vmcnt(" #N ")" ::: "memory")

// Stage a tile (rows x (1<<CPRL) 16B-chunks per row) from global into LDS.
// 256-thread version (attn). LDS[r][bir] holds global[r][bir ^ ((r&7)<<4)].
template <int CPRL>
static __device__ __forceinline__ void stage_tile(const char* g0, long gstride,
                                                  char* lds) {
  int tid = threadIdx.x;
  int lane = tid & 63, wv = tid >> 6;
#pragma unroll
  for (int it = 0; it < 4; ++it) {
    int cb = wv * 256 + it * 64;  // wave-uniform chunk base
    int c = cb + lane;
    int r = c >> CPRL;
    int bir = (c & ((1 << CPRL) - 1)) << 4;
    int sbir = bir ^ ((r & 7) << 4);
    GLDS(g0 + (long)r * gstride + sbir, lds + cb * 16);
  }
}

// ---------------- prep kernels ----------------

__global__ __launch_bounds__(256) void conv_x(const float* __restrict__ x,
                                              u16* __restrict__ y) {
  size_t i = ((size_t)blockIdx.x * 256 + threadIdx.x) * 4;
  float4 v = *(const float4*)(x + i);
  ushort4 o = make_ushort4(f2bf(v.x), f2bf(v.y), f2bf(v.z), f2bf(v.w));
  *(ushort4*)(y + i) = o;
}

// dst[n*K + k] = bf16(src[k*N + n]);  grid: (N/32, K/32), block (32,8)
__global__ __launch_bounds__(256) void transpose_bf16(
    const float* __restrict__ src, u16* __restrict__ dst, int K, int N) {
  __shared__ float t[32][33];
  int n0 = blockIdx.x * 32, k0 = blockIdx.y * 32;
  int tx = threadIdx.x, ty = threadIdx.y;
#pragma unroll
  for (int i = 0; i < 4; ++i)
    t[ty + 8 * i][tx] = src[(size_t)(k0 + ty + 8 * i) * N + n0 + tx];
  __syncthreads();
#pragma unroll
  for (int i = 0; i < 4; ++i)
    dst[(size_t)(n0 + ty + 8 * i) * K + k0 + tx] = f2bf(t[tx][ty + 8 * i]);
}

__global__ __launch_bounds__(256) void prep_cstab(const int* __restrict__ pos,
                                                  float2* __restrict__ cs) {
  int i = blockIdx.x * 256 + threadIdx.x;  // [B*S * 64)
  int row = i >> 6, d = i & 63;
  float p = (float)pos[row];
  float inv = expf(-((float)(2 * d) * (1.0f / 128.0f)) * 13.815510557964274f);
  float a = p * inv;
  float s, c;
  sincosf(a, &s, &c);
  cs[i] = make_float2(c, s);
}

// ---------------- pipelined GEMM core (512 threads, 8 waves) ----------------
// Double-buffered global_load_lds staging with COUNTED vmcnt (never 0 in the
// main loop) + raw s_barrier (avoids __syncthreads' vmcnt(0) drain — the m97
// structural stall). Schedule per iteration t (buf p = t&1):
//   vmcnt(LPT)  -> tile t's own loads drained; tile t+1's stay in flight
//   s_barrier   -> all waves drained their share: tile t fully in LDS
//   compute 64 MFMA/wave from buf p (swizzled ds_read_b128, setprio)
//   s_barrier   -> all waves done reading buf p
//   stage tile t+2 into buf p (issue-only; a full K-tile of compute hides it)
// Per-wave tile: (BM/WM) x (BN/WN). LPT = (BM+BN)/64 loads per wave per tile.
template <int BM, int BN, int WM, int WN>
static __device__ __forceinline__ void gemm_core(
    const u16* __restrict__ A, const u16* __restrict__ Bt, int K, int bm,
    int bn, char* Abuf, char* Bbuf,
    f32x4 (&acc)[(BM / WM) / 16][(BN / WN) / 16]) {
  constexpr int MF = (BM / WM) / 16;
  constexpr int NF = (BN / WN) / 16;
  constexpr int ASZ = BM * 128;  // bytes per A buffer (BK=64 bf16 = 128B/row)
  constexpr int BSZ = BN * 128;
  constexpr int LPT = (BM + BN) / 64;

  int tid = threadIdx.x;
  int lane = tid & 63;
  int wid = tid >> 6;
  int l16 = lane & 15, ln4 = lane >> 4;
  int wr = wid / WN, wc = wid % WN;

  const char* ga = (const char*)(A + (size_t)bm * BM * K);
  const char* gb = (const char*)(Bt + (size_t)bn * BN * K);
  long gstride = (long)K * 2;
  int nkt = K / 64;

  auto STAGE = [&](int t, int p) {
    const char* a0 = ga + t * 128;
    const char* b0 = gb + t * 128;
#pragma unroll
    for (int it = 0; it < BM / 64; ++it) {
      int c = it * 512 + tid;
      int r = c >> 3, bir = (c & 7) << 4;
      GLDS(a0 + (long)r * gstride + (bir ^ ((r & 7) << 4)),
           Abuf + p * ASZ + c * 16);
    }
#pragma unroll
    for (int it = 0; it < BN / 64; ++it) {
      int c = it * 512 + tid;
      int r = c >> 3, bir = (c & 7) << 4;
      GLDS(b0 + (long)r * gstride + (bir ^ ((r & 7) << 4)),
           Bbuf + p * BSZ + c * 16);
    }
  };

  STAGE(0, 0);
  STAGE(1, 1);

#pragma unroll 1
  for (int t = 0; t < nkt; ++t) {
    int p = t & 1;
    if (t < nkt - 1) {
      if constexpr (LPT == 8) WAITV(8);
      else WAITV(6);
    } else {
      WAITV(0);
    }
    __builtin_amdgcn_s_barrier();
    __builtin_amdgcn_sched_barrier(0);

    const char* Ab = Abuf + p * ASZ;
    const char* Bb = Bbuf + p * BSZ;
    bf16x8 af[MF][2];
#pragma unroll
    for (int m = 0; m < MF; ++m) {
      int r = wr * (BM / WM) + m * 16 + l16;
#pragma unroll
      for (int kk = 0; kk < 2; ++kk)
        af[m][kk] = *(const bf16x8*)(Ab + r * 128 +
                                     ((kk * 64 + ln4 * 16) ^ ((r & 7) << 4)));
    }
#pragma unroll
    for (int np = 0; np < NF / 2; ++np) {
      bf16x8 bfr[2][2];
#pragma unroll
      for (int j = 0; j < 2; ++j) {
        int r = wc * (BN / WN) + (np * 2 + j) * 16 + l16;
#pragma unroll
        for (int kk = 0; kk < 2; ++kk)
          bfr[j][kk] =
              *(const bf16x8*)(Bb + r * 128 +
                               ((kk * 64 + ln4 * 16) ^ ((r & 7) << 4)));
      }
      __builtin_amdgcn_s_setprio(1);
#pragma unroll
      for (int kk = 0; kk < 2; ++kk)
#pragma unroll
        for (int m = 0; m < MF; ++m)
#pragma unroll
          for (int j = 0; j < 2; ++j)
            acc[m][np * 2 + j] =
                MFMA16(af[m][kk], bfr[j][kk], acc[m][np * 2 + j]);
      __builtin_amdgcn_s_setprio(0);
    }

    __builtin_amdgcn_sched_barrier(0);
    __builtin_amdgcn_s_barrier();
    if (t + 2 < nkt) STAGE(t + 2, p);
  }
}

// ---------------- GEMM1: QKV projection + bias + RoPE ----------------
// C[4096,3072] = Xb @ Wqkv_t^T. BM=BN=256, 8 waves as 4(M)x2(N): per-wave
// 64 rows x 128 cols, so each wave owns exactly one 128-col head-block and
// RoPE pairs (d, d+64) = acc frags (bi, bi+4) are lane-local.
// Q is pre-scaled by SCALE_ (folded out of the attention softmax).
__global__ __launch_bounds__(512) void gemm_qkv(
    const u16* __restrict__ Xb, const u16* __restrict__ Wt,
    const float* __restrict__ bq, const float* __restrict__ bk,
    const float* __restrict__ bv, const float2* __restrict__ cstab,
    u16* __restrict__ Qh, u16* __restrict__ Kh, u16* __restrict__ Vt) {
  __shared__ __align__(16) char Abuf[2 * 256 * 128];  // 64 KB
  __shared__ __align__(16) char Bbuf[2 * 256 * 128];  // 64 KB
  int bid = blockIdx.x;
  int swz = (bid & 7) * 24 + (bid >> 3);  // XCD-contiguous chunks (192=8*24)
  int bm = swz / 12, bn = swz % 12;

  f32x4 acc[4][8] = {};
  gemm_core<256, 256, 4, 2>(Xb, Wt, 2048, bm, bn, Abuf, Bbuf, acc);

  int tid = threadIdx.x, lane = tid & 63, wid = tid >> 6;
  int l16 = lane & 15, ln4 = lane >> 4;
  int wr = wid >> 1, wc = wid & 1;

  int cb = bn * 2 + wc;  // global 128-col head-block
  int region, hh;
  const float* bias;
  if (cb < 16) {
    region = 0; hh = cb; bias = bq;
  } else if (cb < 20) {
    region = 1; hh = cb - 16; bias = bk;
  } else {
    region = 2; hh = cb - 20; bias = bv;
  }
  float postscale = (region == 0) ? SCALE_ : 1.0f;

#pragma unroll
  for (int bi = 0; bi < 4; ++bi) {
    int dlo = bi * 16 + l16;  // 0..63
    float blo = bias[hh * 128 + dlo];
    float bhi = bias[hh * 128 + dlo + 64];
#pragma unroll
    for (int m = 0; m < 4; ++m) {
      int rbase = bm * 256 + wr * 64 + m * 16 + ln4 * 4;
      int bb = rbase >> 11;   // batch
      int s0 = rbase & 2047;  // seq
      if (region == 2) {
        // V: no rope; transposed store Vt[b][kvh][d][s], 4 consecutive s
        u16 pl[4], ph[4];
#pragma unroll
        for (int reg = 0; reg < 4; ++reg) {
          pl[reg] = f2bf(acc[m][bi][reg] + blo);
          ph[reg] = f2bf(acc[m][bi + 4][reg] + bhi);
        }
        size_t base = ((size_t)(bb * NKV_ + hh) * 128 + dlo) * 2048 + s0;
        *(ushort4*)(Vt + base) = make_ushort4(pl[0], pl[1], pl[2], pl[3]);
        *(ushort4*)(Vt + base + (size_t)64 * 2048) =
            make_ushort4(ph[0], ph[1], ph[2], ph[3]);
      } else {
#pragma unroll
        for (int reg = 0; reg < 4; ++reg) {
          int rg = rbase + reg;
          int s = rg & 2047;
          float vlo = acc[m][bi][reg] + blo;
          float vhi = acc[m][bi + 4][reg] + bhi;
          float2 cs = cstab[(size_t)rg * 64 + dlo];
          float nl = (vlo * cs.x - vhi * cs.y) * postscale;
          float nh = (vhi * cs.x + vlo * cs.y) * postscale;
          u16* dst = (region == 0)
                         ? Qh + ((size_t)(bb * NH_ + hh) * 2048 + s) * 128
                         : Kh + ((size_t)(bb * NKV_ + hh) * 2048 + s) * 128;
          dst[dlo] = f2bf(nl);
          dst[dlo + 64] = f2bf(nh);
        }
      }
    }
  }
}

// ---------------- attention: causal GQA flash ----------------
// 4 waves, single-buffered 40KB LDS (4 blocks/CU), XCD pinning (bid&7 ->
// (b,kvh): each XCD's L2 sees one 2MB K/V set), defer-max softmax.
__global__ __launch_bounds__(256) void attn(const u16* __restrict__ Qh,
                                            const u16* __restrict__ Kh,
                                            const u16* __restrict__ Vt,
                                            u16* __restrict__ ctx) {
  __shared__ __align__(16) char Ks[16384];   // [64 kv][128 d] swizzled
  __shared__ __align__(16) char Vs[16384];   // [128 d][64 kv] swizzled
  __shared__ __align__(16) char Ps[4][2048]; // per-wave [16 q][64 kv]
  int bid = blockIdx.x;
  int x = bid & 7;           // XCD group = (b, kvh)
  int b = x >> 2, kvh = x & 3;
  int i = bid >> 3;          // 0..127 within XCD group
  int hl = i & 3;            // head within kv group
  int qt = 31 - (i >> 2);    // heavy q-tiles first
  int h = kvh * 4 + hl;
  int q0 = qt * 64;
  int nt = qt + 1;

  int tid = threadIdx.x, lane = tid & 63, w = tid >> 6;
  int l16 = lane & 15, ln4 = lane >> 4;

  bf16x8 qf[4];
  const u16* qrow = Qh + ((size_t)(b * NH_ + h) * 2048 + q0 + w * 16 + l16) * 128;
#pragma unroll
  for (int kk = 0; kk < 4; ++kk)
    qf[kk] = *(const bf16x8*)(qrow + kk * 32 + ln4 * 8);

  f32x4 oacc[8] = {};
  float mrow[4], lsum[4];
#pragma unroll
  for (int r = 0; r < 4; ++r) {
    mrow[r] = -1e30f;
    lsum[r] = 0.0f;
  }

  const char* kbase = (const char*)(Kh + (size_t)(b * NKV_ + kvh) * 2048 * 128);
  const char* vbase = (const char*)(Vt + (size_t)(b * NKV_ + kvh) * 128 * 2048);

#pragma unroll 1
  for (int t = 0; t < nt; ++t) {
    __syncthreads();
    stage_tile<4>(kbase + (size_t)t * 64 * 256, 256, Ks);
    stage_tile<3>(vbase + (size_t)t * 128, 4096, Vs);
    __syncthreads();

    // S = Q K^T
    f32x4 sa[4] = {};
    __builtin_amdgcn_s_setprio(1);
#pragma unroll
    for (int kk = 0; kk < 4; ++kk) {
      bf16x8 kf[4];
#pragma unroll
      for (int n = 0; n < 4; ++n) {
        int r = n * 16 + l16;
        int off = r * 256 + ((kk * 64 + ln4 * 16) ^ ((r & 7) << 4));
        kf[n] = *(const bf16x8*)(Ks + off);
      }
#pragma unroll
      for (int n = 0; n < 4; ++n) sa[n] = MFMA16(qf[kk], kf[n], sa[n]);
    }
    __builtin_amdgcn_s_setprio(0);

    if (t == nt - 1) {
#pragma unroll
      for (int n = 0; n < 4; ++n)
#pragma unroll
        for (int reg = 0; reg < 4; ++reg)
          if (t * 64 + n * 16 + l16 > q0 + w * 16 + ln4 * 4 + reg)
            sa[n][reg] = -1e30f;
    }

    // shuffle-free defer-max test
    float tloc[4];
    int ok = 1;
#pragma unroll
    for (int reg = 0; reg < 4; ++reg) {
      tloc[reg] = fmaxf(fmaxf(sa[0][reg], sa[1][reg]),
                        fmaxf(sa[2][reg], sa[3][reg]));
      ok &= (tloc[reg] <= mrow[reg] + 8.0f);
    }
    if (!__all(ok)) {
#pragma unroll
      for (int reg = 0; reg < 4; ++reg) {
        float tm = tloc[reg];
#pragma unroll
        for (int mk = 1; mk < 16; mk <<= 1) tm = fmaxf(tm, __shfl_xor(tm, mk));
        float mnew = fmaxf(mrow[reg], tm);
        float scl = __expf(mrow[reg] - mnew);
        mrow[reg] = mnew;
        lsum[reg] *= scl;
#pragma unroll
        for (int nf = 0; nf < 8; ++nf) oacc[nf][reg] *= scl;
      }
    }

    // P = exp(S - m) -> wave-private LDS; per-lane lsum partials
#pragma unroll
    for (int reg = 0; reg < 4; ++reg) {
      int prow = ln4 * 4 + reg;
      float rs = 0.0f;
#pragma unroll
      for (int n = 0; n < 4; ++n) {
        float p = __expf(sa[n][reg] - mrow[reg]);
        rs += p;
        int off = prow * 128 + ((2 * (n * 16 + l16)) ^ ((prow & 7) << 4));
        *(u16*)(Ps[w] + off) = f2bf(p);
      }
      lsum[reg] += rs;
    }

    // O += P V
    __builtin_amdgcn_s_setprio(1);
#pragma unroll
    for (int kc = 0; kc < 2; ++kc) {
      int offa = l16 * 128 + ((kc * 64 + ln4 * 16) ^ ((l16 & 7) << 4));
      bf16x8 pa = *(const bf16x8*)(Ps[w] + offa);
#pragma unroll
      for (int nf = 0; nf < 8; ++nf) {
        int r = nf * 16 + l16;
        int off = r * 128 + ((kc * 64 + ln4 * 16) ^ ((r & 7) << 4));
        bf16x8 vf = *(const bf16x8*)(Vs + off);
        oacc[nf] = MFMA16(pa, vf, oacc[nf]);
      }
    }
    __builtin_amdgcn_s_setprio(0);
  }

  // epilogue
#pragma unroll
  for (int reg = 0; reg < 4; ++reg) {
#pragma unroll
    for (int mk = 1; mk < 16; mk <<= 1)
      lsum[reg] += __shfl_xor(lsum[reg], mk);
  }
#pragma unroll
  for (int reg = 0; reg < 4; ++reg) {
    float inv = 1.0f / lsum[reg];
    int s = q0 + w * 16 + ln4 * 4 + reg;
#pragma unroll
    for (int nf = 0; nf < 8; ++nf) {
      ctx[((size_t)(b * 2048 + s)) * 2048 + h * 128 + nf * 16 + l16] =
          f2bf(oacc[nf][reg] * inv);
    }
  }
}

// ---------------- GEMM2: out = ctx @ Wo (fp32 out) ----------------
// BM=128, BN=256, 8 waves as 2(M)x4(N): per-wave 64x64. Grid = 256 blocks
// exactly (1/CU full coverage).
__global__ __launch_bounds__(512) void gemm_out(const u16* __restrict__ Ab,
                                                const u16* __restrict__ Wt,
                                                float* __restrict__ out) {
  __shared__ __align__(16) char Abuf[2 * 128 * 128];  // 32 KB
  __shared__ __align__(16) char Bbuf[2 * 256 * 128];  // 64 KB
  int bid = blockIdx.x;
  int swz = (bid & 7) * 32 + (bid >> 3);  // XCD chunks (256=8*32)
  int bm = swz >> 3, bn = swz & 7;

  f32x4 acc[4][4] = {};
  gemm_core<128, 256, 2, 4>(Ab, Wt, 2048, bm, bn, Abuf, Bbuf, acc);

  int tid = threadIdx.x, lane = tid & 63, wid = tid >> 6;
  int l16 = lane & 15, ln4 = lane >> 4;
  int wr = wid >> 2, wc = wid & 3;

#pragma unroll
  for (int m = 0; m < 4; ++m)
#pragma unroll
    for (int n = 0; n < 4; ++n)
#pragma unroll
      for (int reg = 0; reg < 4; ++reg) {
        int row = bm * 128 + wr * 64 + m * 16 + ln4 * 4 + reg;
        int col = bn * 256 + wc * 64 + n * 16 + l16;
        out[(size_t)row * 2048 + col] = acc[m][n][reg];
      }
}

// ---------------- launch ----------------

extern "C" void kernel_launch(void* const* d_in, const int* in_sizes, int n_in,
                              void* d_out, int out_size, void* d_ws,
                              size_t ws_size, hipStream_t stream) {
  const float* hid = (const float*)d_in[0];
  const int* pos = (const int*)d_in[1];
  const float* Wq = (const float*)d_in[2];
  const float* bq = (const float*)d_in[3];
  const float* Wk = (const float*)d_in[4];
  const float* bk = (const float*)d_in[5];
  const float* Wv = (const float*)d_in[6];
  const float* bv = (const float*)d_in[7];
  const float* Wo = (const float*)d_in[8];
  float* out = (float*)d_out;

  char* ws = (char*)d_ws;
  u16* Xb = (u16*)(ws + 0);                    // 16.78 MB  [4096][2048] bf16
  u16* Wqkvt = (u16*)(ws + 16777216UL);        // 12.58 MB  [3072][2048] bf16
  u16* Wot = (u16*)(ws + 29360128UL);          //  8.39 MB  [2048][2048] bf16
  u16* Qh = (u16*)(ws + 37748736UL);           // 16.78 MB  [B][NH][S][D]
  u16* Kh = (u16*)(ws + 54525952UL);           //  4.19 MB  [B][NKV][S][D]
  u16* Vt = (u16*)(ws + 58720256UL);           //  4.19 MB  [B][NKV][D][S]
  float2* cstab = (float2*)(ws + 62914560UL);  //  2.10 MB  [B*S][64]
  u16* ctx = Xb;  // alias: Xb dead after gemm_qkv

  conv_x<<<8192, 256, 0, stream>>>(hid, Xb);
  transpose_bf16<<<dim3(64, 64), dim3(32, 8), 0, stream>>>(Wq, Wqkvt, 2048,
                                                           2048);
  transpose_bf16<<<dim3(16, 64), dim3(32, 8), 0, stream>>>(
      Wk, Wqkvt + (size_t)2048 * 2048, 2048, 512);
  transpose_bf16<<<dim3(16, 64), dim3(32, 8), 0, stream>>>(
      Wv, Wqkvt + (size_t)2560 * 2048, 2048, 512);
  transpose_bf16<<<dim3(64, 64), dim3(32, 8), 0, stream>>>(Wo, Wot, 2048, 2048);
  prep_cstab<<<1024, 256, 0, stream>>>(pos, cstab);

  gemm_qkv<<<192, 512, 0, stream>>>(Xb, Wqkvt, bq, bk, bv, cstab, Qh, Kh, Vt);
  attn<<<1024, 256, 0, stream>>>(Qh, Kh, Vt, ctx);
  gemm_out<<<256, 512, 0, stream>>>(ctx, Wot, out);
}